// Round 8
// baseline (88.548 us; speedup 1.0000x reference)
//
#include <hip/hip_runtime.h>
#include <hip/hip_bf16.h>

typedef __bf16 bf16x8 __attribute__((ext_vector_type(8)));
typedef float  f32x4  __attribute__((ext_vector_type(4)));

#define LRELU_ALPHA 0.2f
#define LOG2E 1.44269504088896340736f

// native 2^x (single v_exp_f32, no OCML call)
__device__ __forceinline__ float fexp2(float x) {
#if __has_builtin(__builtin_amdgcn_exp2f)
    return __builtin_amdgcn_exp2f(x);
#else
    float r; asm("v_exp_f32 %0, %1" : "=v"(r) : "v"(x)); return r;
#endif
}

// raw barrier: drains LDS (lgkmcnt) but leaves global prefetches (vmcnt) in flight
__device__ __forceinline__ void wg_barrier() {
    asm volatile("s_waitcnt lgkmcnt(0)" ::: "memory");
    __builtin_amdgcn_s_barrier();
    asm volatile("" ::: "memory");
}

// ---------------------------------------------------------------------------
// Kernel 1: h = inp @ W (8 rows/block) -> hb (bf16), f1 = log2e*(h·a1),
// f2 = log2e*(h·a2).
// ---------------------------------------------------------------------------
__global__ __launch_bounds__(128) void gat_prep(
    const float* __restrict__ inp, const float* __restrict__ W,
    const float* __restrict__ a,
    __bf16* __restrict__ hb, float* __restrict__ f1, float* __restrict__ f2)
{
    const int r0 = blockIdx.x << 3;
    const int d  = threadIdx.x;
    __shared__ float sIn[8][128];
    __shared__ float sRed[8][4];
    #pragma unroll
    for (int r = 0; r < 8; ++r)
        sIn[r][d] = inp[(size_t)(r0 + r) * 128 + d];
    __syncthreads();

    float acc[8] = {0.f,0.f,0.f,0.f,0.f,0.f,0.f,0.f};
    #pragma unroll 4
    for (int k = 0; k < 128; ++k) {
        float wv = W[k * 128 + d];
        #pragma unroll
        for (int r = 0; r < 8; ++r) acc[r] += sIn[r][k] * wv;
    }

    const float a1 = a[d], a2 = a[128 + d];
    const int wv = d >> 6;
    #pragma unroll
    for (int r = 0; r < 8; ++r) {
        hb[(size_t)(r0 + r) * 128 + d] = (__bf16)acc[r];
        float t1 = acc[r] * a1;
        float t2 = acc[r] * a2;
        #pragma unroll
        for (int m = 1; m < 64; m <<= 1) {
            t1 += __shfl_xor(t1, m);
            t2 += __shfl_xor(t2, m);
        }
        if ((d & 63) == 0) { sRed[r][wv] = t1; sRed[r][2 + wv] = t2; }
    }
    __syncthreads();
    if (d < 8) {
        f1[r0 + d] = (sRed[d][0] + sRed[d][1]) * LOG2E;
        f2[r0 + d] = (sRed[d][2] + sRed[d][3]) * LOG2E;
    }
}

// ---------------------------------------------------------------------------
// Kernel 2: per-batch max of (prescaled) f1
// ---------------------------------------------------------------------------
__global__ __launch_bounds__(256) void gat_f1max(
    const float* __restrict__ f1, float* __restrict__ f1max)
{
    const int b = blockIdx.x;
    const int t = threadIdx.x;
    float m = -1e30f;
    for (int j = t; j < 2048; j += 256) m = fmaxf(m, f1[b * 2048 + j]);
    #pragma unroll
    for (int k = 1; k < 64; k <<= 1) m = fmaxf(m, __shfl_xor(m, k));
    __shared__ float sm[4];
    if ((t & 63) == 0) sm[t >> 6] = m;
    __syncthreads();
    if (t == 0) f1max[b] = fmaxf(fmaxf(sm[0], sm[1]), fmaxf(sm[2], sm[3]));
}

// ---------------------------------------------------------------------------
// Kernel 3: hb (bf16 [b][n][128]) -> pack: fragment-major bf16 B-operands.
// pack element offset = (b*32 + jt)*8192 + frag*512 + lane*8, frag = D*2+jh.
// Fragment lane(il,kg) elem e = h[jt*64 + jh*32 + kg*8 + e][D*16 + il].
// ---------------------------------------------------------------------------
__global__ __launch_bounds__(256) void gat_pack(
    const __bf16* __restrict__ hb, __bf16* __restrict__ pack)
{
    __shared__ __bf16 tile[64][72];
    const int tid = threadIdx.x;
    const int bidx = blockIdx.x;         // 512 blocks
    const int b  = bidx >> 6;
    const int tI = bidx & 63;
    const int n0 = (tI >> 1) << 6;       // j-range 64
    const int d0 = (tI & 1) << 6;        // d-range 64
    #pragma unroll
    for (int pass = 0; pass < 2; ++pass) {
        int row = (tid >> 3) + (pass << 5);     // j within tile
        int c   = (tid & 7) << 3;               // d within tile
        *(bf16x8*)&tile[row][c] =
            *(const bf16x8*)(hb + (size_t)(b * 2048 + n0 + row) * 128 + d0 + c);
    }
    __syncthreads();
    const int lane = tid & 63;
    const int il = lane & 15;
    const int kg = lane >> 4;
    #pragma unroll
    for (int pass = 0; pass < 2; ++pass) {
        const int f  = (tid >> 6) + (pass << 2);   // fragment 0..7 of this block
        const int Dl = f >> 1;
        const int jh = f & 1;
        union { __bf16 e[8]; bf16x8 v; } u;
        #pragma unroll
        for (int e = 0; e < 8; ++e)
            u.e[e] = tile[(jh << 5) + (kg << 3) + e][(Dl << 4) + il];
        const size_t off = (((size_t)(b << 5) + (n0 >> 6)) << 13)
                         + ((size_t)((((d0 >> 4) + Dl) << 1) | jh) << 9)
                         + (lane << 3);
        *(bf16x8*)(pack + off) = u.v;
    }
}

// ---------------------------------------------------------------------------
// Kernel 4 v8: barrier-free fused attention with in-kernel adj bit-packing.
// 512 thr (8 waves = 2 ig x 4 dq), block = 32 i-rows x 128 d.
// Pre-pass: stream own 256KB adj slice (coalesced) -> 8.5KB LDS bit array.
// Main loop (NO barriers): lane computes its own A-frag P values in regs
// (adj via 2 ds_read_u8, f1 via broadcast LDS), B from packed global
// (coalesced, L2/XCD-resident). Denominator via ones-B MFMA (accd).
// ---------------------------------------------------------------------------
__device__ __forceinline__ float pone(float fv, unsigned int by, int e,
                                      float C1p, float C2p) {
    float arg = fmaxf(fv + C1p, __builtin_fmaf(LRELU_ALPHA, fv, C2p));
    float mk  = (float)((by >> e) & 1u);
    return fexp2(__builtin_fmaf(arg, mk, -1000.f));   // masked: 2^-1000 -> 0
}

__global__ __launch_bounds__(512, 4) void gat_attn8(
    const int* __restrict__ adj, const __bf16* __restrict__ hb,
    const __bf16* __restrict__ pack, const float* __restrict__ f1g,
    const float* __restrict__ f2g, const float* __restrict__ f1maxg,
    float* __restrict__ out)
{
    const int bid = ((blockIdx.x & 7) << 6) | (blockIdx.x >> 3);  // batch<->XCD
    const int b  = bid >> 6;
    const int i0 = (bid & 63) << 5;
    const int tid = threadIdx.x;

    __shared__ float f1s[2048];                 // 8 KB
    __shared__ unsigned int bits[32 * 68];      // 8.5 KB, row stride 272 B

    *(float4*)&f1s[tid << 2] = *(const float4*)&f1g[(b << 11) + (tid << 2)];

    // ---- pre-pass: rows i0..i0+31, one row per pass, fully coalesced ----
    {
        const int* abase = adj + (((size_t)((b << 11) + i0)) << 11) + (tid << 2);
        int4 c0 = *(const int4*)(abase);
        int4 c1 = *(const int4*)(abase + 2048);
        for (int p = 0; p < 32; ++p) {
            int4 c2 = *(const int4*)(abase + (((p + 2) & 31) << 11));
            unsigned int u = (unsigned)(c0.x > 0)        | ((unsigned)(c0.y > 0) << 1)
                           | ((unsigned)(c0.z > 0) << 2) | ((unsigned)(c0.w > 0) << 3);
            u |= ((unsigned)__shfl_xor((int)u, 1)) << 4;
            u |= ((unsigned)__shfl_xor((int)u, 2)) << 8;
            u |= ((unsigned)__shfl_xor((int)u, 4)) << 16;
            if ((tid & 7) == 0) bits[p * 68 + (tid >> 3)] = u;
            c0 = c1; c1 = c2;
        }
    }

    // ---- per-lane mapping ----
    const int w    = tid >> 6;
    const int lane = tid & 63;
    const int il   = lane & 15;
    const int kg   = lane >> 4;
    const int ig   = w & 1;             // i-group (rows ig*16..+16)
    const int dq   = w >> 1;            // d-quarter (cols dq*32..+32)
    const int row  = (ig << 4) + il;    // A-row this lane feeds

    const float fm  = f1maxg[b];
    const float f2v = f2g[(b << 11) + i0 + row];
    const float z   = f2v + fm;
    const float M   = fmaxf(z, LRELU_ALPHA * z);        // exact bound: p <= 1
    const float C1p = f2v - M + 1000.f;
    const float C2p = __builtin_fmaf(LRELU_ALPHA, f2v, 1000.f - M);

    const unsigned char* bitsB = (const unsigned char*)bits;
    const int rb  = row * 272 + kg;     // byte base: + t*8 (+4 for k-half 1)
    const int kgo = kg << 3;

    const __bf16* pB = pack + ((size_t)b << 18) + (dq << 11) + (lane << 3);

    f32x4 acc0 = {0.f,0.f,0.f,0.f}, acc1 = {0.f,0.f,0.f,0.f};
    f32x4 accd = {0.f,0.f,0.f,0.f};
    union { __bf16 e[8]; bf16x8 v; } ones;
    #pragma unroll
    for (int x = 0; x < 8; ++x) ones.e[x] = (__bf16)1.0f;
    const bf16x8 onesv = ones.v;

    // B tile 0 prefetch (stays in flight across the lgkm-only barrier)
    bf16x8 Bc0 = *(const bf16x8*)(pB);
    bf16x8 Bc1 = *(const bf16x8*)(pB + 512);
    bf16x8 Bc2 = *(const bf16x8*)(pB + 1024);
    bf16x8 Bc3 = *(const bf16x8*)(pB + 1536);

    wg_barrier();                       // bits + f1s ready (ONLY barrier)

    for (int t = 0; t < 32; ++t) {
        const __bf16* pBn = pB + ((size_t)((t + 1) & 31) << 13);
        bf16x8 Bn0 = *(const bf16x8*)(pBn);
        bf16x8 Bn1 = *(const bf16x8*)(pBn + 512);
        bf16x8 Bn2 = *(const bf16x8*)(pBn + 1024);
        bf16x8 Bn3 = *(const bf16x8*)(pBn + 1536);

        const unsigned int by0 = bitsB[rb + (t << 3)];
        const unsigned int by1 = bitsB[rb + (t << 3) + 4];
        float4 fa = *(const float4*)&f1s[(t << 6) + kgo];
        float4 fb = *(const float4*)&f1s[(t << 6) + kgo + 4];
        float4 fc = *(const float4*)&f1s[(t << 6) + 32 + kgo];
        float4 fd = *(const float4*)&f1s[(t << 6) + 32 + kgo + 4];

        union { __bf16 e[8]; bf16x8 v; } pa0, pa1;
        pa0.e[0] = (__bf16)pone(fa.x, by0, 0, C1p, C2p);
        pa0.e[1] = (__bf16)pone(fa.y, by0, 1, C1p, C2p);
        pa0.e[2] = (__bf16)pone(fa.z, by0, 2, C1p, C2p);
        pa0.e[3] = (__bf16)pone(fa.w, by0, 3, C1p, C2p);
        pa0.e[4] = (__bf16)pone(fb.x, by0, 4, C1p, C2p);
        pa0.e[5] = (__bf16)pone(fb.y, by0, 5, C1p, C2p);
        pa0.e[6] = (__bf16)pone(fb.z, by0, 6, C1p, C2p);
        pa0.e[7] = (__bf16)pone(fb.w, by0, 7, C1p, C2p);
        pa1.e[0] = (__bf16)pone(fc.x, by1, 0, C1p, C2p);
        pa1.e[1] = (__bf16)pone(fc.y, by1, 1, C1p, C2p);
        pa1.e[2] = (__bf16)pone(fc.z, by1, 2, C1p, C2p);
        pa1.e[3] = (__bf16)pone(fc.w, by1, 3, C1p, C2p);
        pa1.e[4] = (__bf16)pone(fd.x, by1, 4, C1p, C2p);
        pa1.e[5] = (__bf16)pone(fd.y, by1, 5, C1p, C2p);
        pa1.e[6] = (__bf16)pone(fd.z, by1, 6, C1p, C2p);
        pa1.e[7] = (__bf16)pone(fd.w, by1, 7, C1p, C2p);

        acc0 = __builtin_amdgcn_mfma_f32_16x16x32_bf16(pa0.v, Bc0, acc0, 0, 0, 0);
        acc0 = __builtin_amdgcn_mfma_f32_16x16x32_bf16(pa1.v, Bc1, acc0, 0, 0, 0);
        acc1 = __builtin_amdgcn_mfma_f32_16x16x32_bf16(pa0.v, Bc2, acc1, 0, 0, 0);
        acc1 = __builtin_amdgcn_mfma_f32_16x16x32_bf16(pa1.v, Bc3, acc1, 0, 0, 0);
        accd = __builtin_amdgcn_mfma_f32_16x16x32_bf16(pa0.v, onesv, accd, 0, 0, 0);
        accd = __builtin_amdgcn_mfma_f32_16x16x32_bf16(pa1.v, onesv, accd, 0, 0, 0);

        Bc0 = Bn0; Bc1 = Bn1; Bc2 = Bn2; Bc3 = Bn3;
    }

    // ---- epilogue: C row = kg*4+r, col = il; accd[r] = row denominator ----
    #pragma unroll
    for (int r = 0; r < 4; ++r) {
        const int orow = (kg << 2) + r;
        const float dn = accd[r];
        const size_t g0 = (((size_t)(b << 11) + i0 + (ig << 4) + orow) << 7)
                          + (dq << 5) + il;
        float v, e;
        v = acc0[r] / dn; e = (v > 0.f) ? v : (__expf(v) - 1.f);
        out[g0] = e + (float)hb[g0];
        v = acc1[r] / dn; e = (v > 0.f) ? v : (__expf(v) - 1.f);
        out[g0 + 16] = e + (float)hb[g0 + 16];
    }
}

// ---------------------------------------------------------------------------
extern "C" void kernel_launch(void* const* d_in, const int* in_sizes, int n_in,
                              void* d_out, int out_size, void* d_ws, size_t ws_size,
                              hipStream_t stream)
{
    const float* inp = (const float*)d_in[0];
    const int*   adj = (const int*)d_in[1];
    const float* W   = (const float*)d_in[2];
    const float* a   = (const float*)d_in[3];
    float* out = (float*)d_out;

    // workspace layout (~8.2 MB)
    char* ws = (char*)d_ws;
    __bf16* hb    = (__bf16*)ws;                       // 4 MB
    __bf16* pack  = (__bf16*)(ws + (4 << 20));         // 4 MB
    float*  f1    = (float*)(ws + (8 << 20));          // 64 KB
    float*  f2    = (float*)(ws + (8 << 20) + 65536);
    float*  f1max = (float*)(ws + (8 << 20) + 131072);

    gat_prep<<<2048, 128, 0, stream>>>(inp, W, a, hb, f1, f2);
    gat_f1max<<<8, 256, 0, stream>>>(f1, f1max);
    gat_pack<<<512, 256, 0, stream>>>(hb, pack);
    gat_attn8<<<512, 512, 0, stream>>>(adj, hb, pack, f1, f2, f1max, out);
}

// Round 9
// 66.750 us; speedup vs baseline: 1.3266x; 1.3266x over previous
//
#include <hip/hip_runtime.h>
#include <hip/hip_bf16.h>

typedef __bf16 bf16x8 __attribute__((ext_vector_type(8)));
typedef float  f32x4  __attribute__((ext_vector_type(4)));

#define LRELU_ALPHA 0.2f
#define LOG2E 1.44269504088896340736f

// native 2^x (single v_exp_f32, no OCML call)
__device__ __forceinline__ float fexp2(float x) {
#if __has_builtin(__builtin_amdgcn_exp2f)
    return __builtin_amdgcn_exp2f(x);
#else
    float r; asm("v_exp_f32 %0, %1" : "=v"(r) : "v"(x)); return r;
#endif
}

// raw barrier: drains LDS (lgkmcnt) but leaves global prefetches (vmcnt) in flight
__device__ __forceinline__ void wg_barrier() {
    asm volatile("s_waitcnt lgkmcnt(0)" ::: "memory");
    __builtin_amdgcn_s_barrier();
    asm volatile("" ::: "memory");
}

// ---------------------------------------------------------------------------
// Kernel 1: h = inp @ W (8 rows/block) -> hb (bf16), f1 = log2e*(h·a1),
// f2 = log2e*(h·a2).
// ---------------------------------------------------------------------------
__global__ __launch_bounds__(128) void gat_prep(
    const float* __restrict__ inp, const float* __restrict__ W,
    const float* __restrict__ a,
    __bf16* __restrict__ hb, float* __restrict__ f1, float* __restrict__ f2)
{
    const int r0 = blockIdx.x << 3;
    const int d  = threadIdx.x;
    __shared__ float sIn[8][128];
    __shared__ float sRed[8][4];
    #pragma unroll
    for (int r = 0; r < 8; ++r)
        sIn[r][d] = inp[(size_t)(r0 + r) * 128 + d];
    __syncthreads();

    float acc[8] = {0.f,0.f,0.f,0.f,0.f,0.f,0.f,0.f};
    #pragma unroll 4
    for (int k = 0; k < 128; ++k) {
        float wv = W[k * 128 + d];
        #pragma unroll
        for (int r = 0; r < 8; ++r) acc[r] += sIn[r][k] * wv;
    }

    const float a1 = a[d], a2 = a[128 + d];
    const int wv = d >> 6;
    #pragma unroll
    for (int r = 0; r < 8; ++r) {
        hb[(size_t)(r0 + r) * 128 + d] = (__bf16)acc[r];
        float t1 = acc[r] * a1;
        float t2 = acc[r] * a2;
        #pragma unroll
        for (int m = 1; m < 64; m <<= 1) {
            t1 += __shfl_xor(t1, m);
            t2 += __shfl_xor(t2, m);
        }
        if ((d & 63) == 0) { sRed[r][wv] = t1; sRed[r][2 + wv] = t2; }
    }
    __syncthreads();
    if (d < 8) {
        f1[r0 + d] = (sRed[d][0] + sRed[d][1]) * LOG2E;
        f2[r0 + d] = (sRed[d][2] + sRed[d][3]) * LOG2E;
    }
}

// ---------------------------------------------------------------------------
// Kernel 2: per-batch max of (prescaled) f1
// ---------------------------------------------------------------------------
__global__ __launch_bounds__(256) void gat_f1max(
    const float* __restrict__ f1, float* __restrict__ f1max)
{
    const int b = blockIdx.x;
    const int t = threadIdx.x;
    float m = -1e30f;
    for (int j = t; j < 2048; j += 256) m = fmaxf(m, f1[b * 2048 + j]);
    #pragma unroll
    for (int k = 1; k < 64; k <<= 1) m = fmaxf(m, __shfl_xor(m, k));
    __shared__ float sm[4];
    if ((t & 63) == 0) sm[t >> 6] = m;
    __syncthreads();
    if (t == 0) f1max[b] = fmaxf(fmaxf(sm[0], sm[1]), fmaxf(sm[2], sm[3]));
}

// ---------------------------------------------------------------------------
// Kernel 3: hb (bf16 [b][n][128]) -> pack: fragment-major bf16 B-operands.
// pack elem offset = (b*32 + jt)*8192 + frag*512 + lane*8, frag = D*2 + jh32.
// Fragment lane(il,kg) elem e = h[jt*64 + jh32*32 + kg*8 + e][D*16 + il].
// ---------------------------------------------------------------------------
__global__ __launch_bounds__(256) void gat_pack(
    const __bf16* __restrict__ hb, __bf16* __restrict__ pack)
{
    __shared__ __bf16 tile[64][72];
    const int tid = threadIdx.x;
    const int bidx = blockIdx.x;         // 512 blocks
    const int b  = bidx >> 6;
    const int tI = bidx & 63;
    const int n0 = (tI >> 1) << 6;       // j-range 64
    const int d0 = (tI & 1) << 6;        // d-range 64
    #pragma unroll
    for (int pass = 0; pass < 2; ++pass) {
        int row = (tid >> 3) + (pass << 5);
        int c   = (tid & 7) << 3;
        *(bf16x8*)&tile[row][c] =
            *(const bf16x8*)(hb + (size_t)(b * 2048 + n0 + row) * 128 + d0 + c);
    }
    __syncthreads();
    const int lane = tid & 63;
    const int il = lane & 15;
    const int kg = lane >> 4;
    #pragma unroll
    for (int pass = 0; pass < 2; ++pass) {
        const int f  = (tid >> 6) + (pass << 2);
        const int Dl = f >> 1;
        const int jh = f & 1;
        union { __bf16 e[8]; bf16x8 v; } u;
        #pragma unroll
        for (int e = 0; e < 8; ++e)
            u.e[e] = tile[(jh << 5) + (kg << 3) + e][(Dl << 4) + il];
        const size_t off = (((size_t)(b << 5) + (n0 >> 6)) << 13)
                         + ((size_t)((((d0 >> 4) + Dl) << 1) | jh) << 9)
                         + (lane << 3);
        *(bf16x8*)(pack + off) = u.v;
    }
}

// ---------------------------------------------------------------------------
// Kernel 4 v9: wave = 16 rows x 128 d, j-half per block. P computed ONCE per
// lane (its own A-frag), reused across 8 d-group MFMAs + ones-MFMA denom.
// adj streamed in 64-j windows (coalesced) -> LDS bits; B staged to LDS.
// One lgkm barrier per window; global loads always one window in flight.
// Partials: jh=0 -> out (f32), jh=1 -> pO1 (bf16); den -> pD.
// ---------------------------------------------------------------------------
__device__ __forceinline__ float pone9(float fv, unsigned by, int e,
                                       float C1p, float C2p) {
    float arg = fmaxf(fv + C1p, __builtin_fmaf(LRELU_ALPHA, fv, C2p));
    float mk  = (float)((by >> e) & 1u);
    return fexp2(__builtin_fmaf(arg, mk, -1000.f));
}

#define NPACK(AV, ROFF, NB) do {                                              \
    unsigned _u = (unsigned)((AV).x > 0)        | ((unsigned)((AV).y > 0) << 1) \
                | ((unsigned)((AV).z > 0) << 2) | ((unsigned)((AV).w > 0) << 3); \
    _u <<= ((ss & 7) << 2);                                                   \
    _u |= (unsigned)__shfl_xor((int)_u, 1);                                   \
    _u |= (unsigned)__shfl_xor((int)_u, 2);                                   \
    _u |= (unsigned)__shfl_xor((int)_u, 4);                                   \
    if ((ss & 7) == 0) bitsW[NB][((srow + (ROFF)) << 1) + (ss >> 3)] = _u;    \
} while (0)

#define STAGE(NB) do {                                                        \
    NPACK(A0, 0, NB); NPACK(A1, 16, NB); NPACK(A2, 32, NB); NPACK(A3, 48, NB);\
    *(int4*)&BLs[NB][(tid << 3)]        = B0;                                 \
    *(int4*)&BLs[NB][(tid << 3) + 2048] = B1;                                 \
    *(int4*)&BLs[NB][(tid << 3) + 4096] = B2;                                 \
    *(int4*)&BLs[NB][(tid << 3) + 6144] = B3;                                 \
} while (0)

#define ISSUE(WN) do {                                                        \
    const int _o = (WN) << 6;                                                 \
    A0 = *(const int4*)(aP0 + _o);                                            \
    A1 = *(const int4*)(aP1 + _o);                                            \
    A2 = *(const int4*)(aP2 + _o);                                            \
    A3 = *(const int4*)(aP3 + _o);                                            \
    const __bf16* _ps = pkB + ((size_t)(WN) << 13);                           \
    B0 = *(const int4*)(_ps);                                                 \
    B1 = *(const int4*)(_ps + 2048);                                          \
    B2 = *(const int4*)(_ps + 4096);                                          \
    B3 = *(const int4*)(_ps + 6144);                                          \
} while (0)

#define KSTEP(WN, CB, KS) do {                                                \
    const unsigned _d = bitsW[CB][((wrow + il) << 1) + (KS)];                 \
    const unsigned by = (_d >> (kg << 3)) & 0xffu;                            \
    const float4 fa = *(const float4*)&f1s[((WN) << 6) + ((KS) << 5) + (kg << 3)];     \
    const float4 fb = *(const float4*)&f1s[((WN) << 6) + ((KS) << 5) + (kg << 3) + 4]; \
    union { __bf16 e[8]; bf16x8 v; } pa;                                      \
    pa.e[0] = (__bf16)pone9(fa.x, by, 0, C1p, C2p);                           \
    pa.e[1] = (__bf16)pone9(fa.y, by, 1, C1p, C2p);                           \
    pa.e[2] = (__bf16)pone9(fa.z, by, 2, C1p, C2p);                           \
    pa.e[3] = (__bf16)pone9(fa.w, by, 3, C1p, C2p);                           \
    pa.e[4] = (__bf16)pone9(fb.x, by, 4, C1p, C2p);                           \
    pa.e[5] = (__bf16)pone9(fb.y, by, 5, C1p, C2p);                           \
    pa.e[6] = (__bf16)pone9(fb.z, by, 6, C1p, C2p);                           \
    pa.e[7] = (__bf16)pone9(fb.w, by, 7, C1p, C2p);                           \
    accd = __builtin_amdgcn_mfma_f32_16x16x32_bf16(pa.v, onesv, accd, 0,0,0); \
    bf16x8 Bf0 = *(const bf16x8*)&BLs[CB][((0<<1)|(KS)) << 9 | (lane << 3)];  \
    bf16x8 Bf1 = *(const bf16x8*)&BLs[CB][((1<<1)|(KS)) << 9 | (lane << 3)];  \
    bf16x8 Bf2 = *(const bf16x8*)&BLs[CB][((2<<1)|(KS)) << 9 | (lane << 3)];  \
    bf16x8 Bf3 = *(const bf16x8*)&BLs[CB][((3<<1)|(KS)) << 9 | (lane << 3)];  \
    bf16x8 Bf4 = *(const bf16x8*)&BLs[CB][((4<<1)|(KS)) << 9 | (lane << 3)];  \
    bf16x8 Bf5 = *(const bf16x8*)&BLs[CB][((5<<1)|(KS)) << 9 | (lane << 3)];  \
    bf16x8 Bf6 = *(const bf16x8*)&BLs[CB][((6<<1)|(KS)) << 9 | (lane << 3)];  \
    bf16x8 Bf7 = *(const bf16x8*)&BLs[CB][((7<<1)|(KS)) << 9 | (lane << 3)];  \
    acc0 = __builtin_amdgcn_mfma_f32_16x16x32_bf16(pa.v, Bf0, acc0, 0,0,0);   \
    acc1 = __builtin_amdgcn_mfma_f32_16x16x32_bf16(pa.v, Bf1, acc1, 0,0,0);   \
    acc2 = __builtin_amdgcn_mfma_f32_16x16x32_bf16(pa.v, Bf2, acc2, 0,0,0);   \
    acc3 = __builtin_amdgcn_mfma_f32_16x16x32_bf16(pa.v, Bf3, acc3, 0,0,0);   \
    acc4 = __builtin_amdgcn_mfma_f32_16x16x32_bf16(pa.v, Bf4, acc4, 0,0,0);   \
    acc5 = __builtin_amdgcn_mfma_f32_16x16x32_bf16(pa.v, Bf5, acc5, 0,0,0);   \
    acc6 = __builtin_amdgcn_mfma_f32_16x16x32_bf16(pa.v, Bf6, acc6, 0,0,0);   \
    acc7 = __builtin_amdgcn_mfma_f32_16x16x32_bf16(pa.v, Bf7, acc7, 0,0,0);   \
} while (0)

__global__ __launch_bounds__(256, 2) void gat_attn9(
    const int* __restrict__ adj, const __bf16* __restrict__ pack,
    const float* __restrict__ f1g, const float* __restrict__ f2g,
    const float* __restrict__ f1maxg,
    float* __restrict__ out, __bf16* __restrict__ pO1, float* __restrict__ pD)
{
    const int bid = ((blockIdx.x & 7) << 6) | (blockIdx.x >> 3);  // batch<->XCD
    const int b   = bid >> 6;
    const int rg  = (bid >> 1) & 31;
    const int jh  = bid & 1;
    const int i0  = rg << 6;            // 64 rows per block
    const int jb0 = jh << 10;           // j-half base
    const int tid = threadIdx.x;

    __shared__ float    f1s[1024];      // 4 KB (this j-half)
    __shared__ __bf16   BLs[2][8192];   // 2 x 16 KB staged B windows
    __shared__ unsigned bitsW[2][128];  // 2 x 512 B adj bits

    *(float4*)&f1s[tid << 2] = *(const float4*)&f1g[(b << 11) + jb0 + (tid << 2)];

    const int w    = tid >> 6;
    const int lane = tid & 63;
    const int il   = lane & 15;
    const int kg   = lane >> 4;
    const int wrow = w << 4;

    // staging maps
    const int srow = tid >> 4;          // +{0,16,32,48}
    const int ss   = tid & 15;
    const size_t growb = (size_t)(b << 11) + i0;
    const int* aP0 = adj + ((growb + srow)      << 11) + jb0 + (ss << 2);
    const int* aP1 = adj + ((growb + srow + 16) << 11) + jb0 + (ss << 2);
    const int* aP2 = adj + ((growb + srow + 32) << 11) + jb0 + (ss << 2);
    const int* aP3 = adj + ((growb + srow + 48) << 11) + jb0 + (ss << 2);
    const __bf16* pkB = pack + ((size_t)b << 18) + ((size_t)(jh << 4) << 13) + (tid << 3);

    // P math constants (global stabilizer -> halves combine exactly)
    const float fm  = f1maxg[b];
    const float f2v = f2g[(b << 11) + i0 + wrow + il];
    const float z   = f2v + fm;
    const float M   = fmaxf(z, LRELU_ALPHA * z);
    const float C1p = f2v - M + 1000.f;
    const float C2p = __builtin_fmaf(LRELU_ALPHA, f2v, 1000.f - M);

    f32x4 acc0 = {0,0,0,0}, acc1 = {0,0,0,0}, acc2 = {0,0,0,0}, acc3 = {0,0,0,0};
    f32x4 acc4 = {0,0,0,0}, acc5 = {0,0,0,0}, acc6 = {0,0,0,0}, acc7 = {0,0,0,0};
    f32x4 accd = {0,0,0,0};
    union { __bf16 e[8]; bf16x8 v; } ones;
    #pragma unroll
    for (int x = 0; x < 8; ++x) ones.e[x] = (__bf16)1.0f;
    const bf16x8 onesv = ones.v;

    int4 A0, A1, A2, A3, B0, B1, B2, B3;

    // prologue: window 0 staged, window 1 in regs
    ISSUE(0);
    STAGE(0);
    ISSUE(1);
    wg_barrier();

    for (int wn = 0; wn < 16; ++wn) {
        const int cb = wn & 1;
        KSTEP(wn, cb, 0);
        KSTEP(wn, cb, 1);
        if (wn < 15) {
            STAGE(cb ^ 1);              // window wn+1 (regs -> LDS; vmcnt auto)
            if (wn < 14) ISSUE(wn + 2); // keep one window in flight
            wg_barrier();
        }
    }

    // ---- write partials ----
    const size_t rowg = (size_t)(b << 11) + i0 + wrow;
    if (jh == 0) {
        #pragma unroll
        for (int r = 0; r < 4; ++r) {
            const size_t rb2 = (rowg + (kg << 2) + r) << 7;
            out[rb2 + ( 0 << 4) + il] = acc0[r];
            out[rb2 + ( 1 << 4) + il] = acc1[r];
            out[rb2 + ( 2 << 4) + il] = acc2[r];
            out[rb2 + ( 3 << 4) + il] = acc3[r];
            out[rb2 + ( 4 << 4) + il] = acc4[r];
            out[rb2 + ( 5 << 4) + il] = acc5[r];
            out[rb2 + ( 6 << 4) + il] = acc6[r];
            out[rb2 + ( 7 << 4) + il] = acc7[r];
        }
    } else {
        #pragma unroll
        for (int r = 0; r < 4; ++r) {
            const size_t rb2 = (rowg + (kg << 2) + r) << 7;
            pO1[rb2 + ( 0 << 4) + il] = (__bf16)acc0[r];
            pO1[rb2 + ( 1 << 4) + il] = (__bf16)acc1[r];
            pO1[rb2 + ( 2 << 4) + il] = (__bf16)acc2[r];
            pO1[rb2 + ( 3 << 4) + il] = (__bf16)acc3[r];
            pO1[rb2 + ( 4 << 4) + il] = (__bf16)acc4[r];
            pO1[rb2 + ( 5 << 4) + il] = (__bf16)acc5[r];
            pO1[rb2 + ( 6 << 4) + il] = (__bf16)acc6[r];
            pO1[rb2 + ( 7 << 4) + il] = (__bf16)acc7[r];
        }
    }
    if (il == 0) {
        #pragma unroll
        for (int r = 0; r < 4; ++r)
            pD[(jh << 14) + rowg + (kg << 2) + r] = accd[r];
    }
}

// ---------------------------------------------------------------------------
// Kernel 5: combine halves, normalize, elu, residual. io aliases out (reads
// jh=0 partial, writes final) — read-before-write per element, same thread.
// ---------------------------------------------------------------------------
__global__ __launch_bounds__(256) void gat_combine(
    float* io, const __bf16* __restrict__ p1,
    const float* __restrict__ pD, const __bf16* __restrict__ hb)
{
    const int idx = blockIdx.x * 256 + threadIdx.x;    // 0..262143
    const size_t base = (size_t)idx << 3;
    const int row = (int)(base >> 7);
    const float den = pD[row] + pD[16384 + row];
    float4 o0a = *(const float4*)(io + base);
    float4 o0b = *(const float4*)(io + base + 4);
    bf16x8 o1 = *(const bf16x8*)(p1 + base);
    bf16x8 hv = *(const bf16x8*)(hb + base);
    float res[8];
    #pragma unroll
    for (int e = 0; e < 8; ++e) {
        float o = ((e < 4) ? ((const float*)&o0a)[e] : ((const float*)&o0b)[e - 4])
                + (float)o1[e];
        float v = o / den;
        float el = (v > 0.f) ? v : (__expf(v) - 1.f);
        res[e] = el + (float)hv[e];
    }
    *(float4*)(io + base)     = (float4){res[0], res[1], res[2], res[3]};
    *(float4*)(io + base + 4) = (float4){res[4], res[5], res[6], res[7]};
}

// ---------------------------------------------------------------------------
extern "C" void kernel_launch(void* const* d_in, const int* in_sizes, int n_in,
                              void* d_out, int out_size, void* d_ws, size_t ws_size,
                              hipStream_t stream)
{
    const float* inp = (const float*)d_in[0];
    const int*   adj = (const int*)d_in[1];
    const float* W   = (const float*)d_in[2];
    const float* a   = (const float*)d_in[3];
    float* out = (float*)d_out;

    // workspace layout (~12.4 MB)
    char* ws = (char*)d_ws;
    __bf16* hb    = (__bf16*)ws;                          // 4 MB
    __bf16* pack  = (__bf16*)(ws + (4 << 20));            // 4 MB
    __bf16* pO1   = (__bf16*)(ws + (8 << 20));            // 4 MB (jh=1 partial)
    float*  pD    = (float*)(ws + (12 << 20));            // 128 KB
    float*  f1    = (float*)(ws + (12 << 20) + 131072);   // 64 KB
    float*  f2    = (float*)(ws + (12 << 20) + 131072 + 65536);
    float*  f1max = (float*)(ws + (12 << 20) + 131072 + 131072);

    gat_prep<<<2048, 128, 0, stream>>>(inp, W, a, hb, f1, f2);
    gat_f1max<<<8, 256, 0, stream>>>(f1, f1max);
    gat_pack<<<512, 256, 0, stream>>>(hb, pack);
    gat_attn9<<<512, 256, 0, stream>>>(adj, pack, f1, f2, f1max, out, pO1, pD);
    gat_combine<<<1024, 256, 0, stream>>>(out, pO1, pD, hb);
}